// Round 9
// baseline (2293.083 us; speedup 1.0000x reference)
//
#include <hip/hip_runtime.h>
#include <math.h>

// ---------------------------------------------------------------------------
// InvKin (R16): k-split thread pairs for occupancy.
// R15 post-mortem: v_pk_fma_f32 is 4 cyc/wave64 (2x work, same ALU width)
// -> zero throughput vs scalar v_fma (2 cyc); busy time went UP (109 vs
// 95us). pk dead. Heavies remain stall-bound: wall ~3x VALU-busy at 31%
// occupancy; h[64]=64 VGPR pins ~80 total.
// R16: lanes l (even) / l^1 share one row. Each holds HALF the h vector
// (h[32], k in [32q,32q+32), q=lane&1) -> ~60 VGPR target (<=64 band,
// 8 waves/SIMD per m69 quantization). Partial dots + one shfl_xor(.,1)
// +add per unit give full z in both lanes. Weight addrs become per-lane
// (+32q) -> vector loads (vmcnt domain), decoupled from the lgkm-counted
// shuffle chains. Stats: even lanes contribute (w gate), rs8 unchanged.
// Stores: even lane planes 0-3, odd 4-7 (contiguous 512B half-wave).
// k_final: even lane writes thetas, odd computes sincos+FK block.
// Cost: +64 combine shuffles/row (+~18% wave instr) vs 2x latency hiding.
//   P1 k_stats_x : x second moments   P2 k_fin1: fold BN1
//   P3 k_z2 : h1 -> z2 -> bf16 planes + fused BN2 stats (paired)
//   P4 k_fin_bn   P5 k_z3 (paired, in place)   P6 k_fin_bn
//   P7 k_final (paired)
// Fallback path (small ws): exact R1 kernel set (verified PASS).
// ---------------------------------------------------------------------------

static constexpr float kEps = 1e-5f;

#define HEAVY_BOUNDS __launch_bounds__(256) __attribute__((amdgpu_waves_per_eu(4, 8)))

// shared ws fp32 indices (both paths)
#define WS_STAT9 0
#define WS_SUM2  16
#define WS_SSQ2  80
#define WS_SUM3  144
#define WS_SSQ3  208
#define WS_W1P   288    // [64][3] fp32 (BN1-folded)
#define WS_C1    480    // [64]
// fast path only
#define FP_S2    8192
#define FP_C2    8256
#define FP_S3    8320
#define FP_C3    8384
// fallback (R1) only — may overlap FP_* since only one path ever runs
#define RC_W2P   544
#define RC_C2    4640
#define RC_W3P   4704
#define RC_C3    8800
// z buffer: byte offset 65536 (ushort index 32768)
#define ZB_U16   32768

// packed bf16x2 convert, round-to-nearest-even
__device__ __forceinline__ unsigned packbf2(float a, float b) {
  unsigned r;
  asm("v_cvt_pk_bf16_f32 %0, %1, %2" : "=v"(r) : "v"(a), "v"(b));
  return r;
}
__device__ __forceinline__ void unpack2(unsigned w, float& lo, float& hi) {
  lo = __builtin_bit_cast(float, w << 16);
  hi = __builtin_bit_cast(float, w & 0xffff0000u);
}

__device__ __forceinline__ float wred64(float v) {
  v += __shfl_xor(v, 32, 64);
  v += __shfl_xor(v, 16, 64);
  v += __shfl_xor(v, 8, 64);
  v += __shfl_xor(v, 4, 64);
  v += __shfl_xor(v, 2, 64);
  v += __shfl_xor(v, 1, 64);
  return v;
}

// butterfly reduce-scatter over 8 values: returns the full 64-lane sum of
// v[lane&7]. Levels 1/2/4 reduce-scatter the 8 units across the 8-lane
// group; levels 8/16/32 all-reduce the survivor across the 8 groups.
__device__ __forceinline__ float rs8(const float* v, int lane) {
  int b0 = lane & 1, b1 = (lane >> 1) & 1, b2 = (lane >> 2) & 1;
  float r[4];
#pragma unroll
  for (int i = 0; i < 4; ++i) {
    float keep = b0 ? v[2 * i + 1] : v[2 * i];
    float send = b0 ? v[2 * i] : v[2 * i + 1];
    r[i] = keep + __shfl_xor(send, 1, 64);
  }
  float t[2];
#pragma unroll
  for (int i = 0; i < 2; ++i) {
    float keep = b1 ? r[2 * i + 1] : r[2 * i];
    float send = b1 ? r[2 * i] : r[2 * i + 1];
    t[i] = keep + __shfl_xor(send, 2, 64);
  }
  float keep = b2 ? t[1] : t[0];
  float send = b2 ? t[0] : t[1];
  float u = keep + __shfl_xor(send, 4, 64);
  u += __shfl_xor(u, 8, 64);
  u += __shfl_xor(u, 16, 64);
  u += __shfl_xor(u, 32, 64);
  return u;
}

// half-row dot: sum over 32 k of w[k]*h[k]
__device__ __forceinline__ float dot32(const float* __restrict__ wr,
                                       const float hin[32]) {
  float a0 = 0.f, a1 = 0.f, a2 = 0.f, a3 = 0.f;
#pragma unroll
  for (int k = 0; k < 32; k += 4) {
    a0 = fmaf(wr[k + 0], hin[k + 0], a0);
    a1 = fmaf(wr[k + 1], hin[k + 1], a1);
    a2 = fmaf(wr[k + 2], hin[k + 2], a2);
    a3 = fmaf(wr[k + 3], hin[k + 3], a3);
  }
  return (a0 + a1) + (a2 + a3);
}

__device__ __forceinline__ float dot64(const float* __restrict__ wr,
                                       const float hin[64]) {
  float a0 = 0.f, a1 = 0.f, a2 = 0.f, a3 = 0.f;
#pragma unroll
  for (int k = 0; k < 64; k += 4) {
    a0 = fmaf(wr[k + 0], hin[k + 0], a0);
    a1 = fmaf(wr[k + 1], hin[k + 1], a1);
    a2 = fmaf(wr[k + 2], hin[k + 2], a2);
    a3 = fmaf(wr[k + 3], hin[k + 3], a3);
  }
  return (a0 + a1) + (a2 + a3);
}

// fused BN stats for one jb-block of 8 units, scalar-z form.
// lane l accumulates global unit (l>>3)*8 + (l&7) == l  (identity map).
__device__ __forceinline__ void stat_rs8s(const float* __restrict__ z, int jb,
                                          int lane, float w,
                                          float& sacc, float& qacc) {
  float s8[8], q8[8];
#pragma unroll
  for (int u = 0; u < 8; ++u) {
    s8[u] = w * z[u];
    q8[u] = s8[u] * z[u];
  }
  float sv = rs8(s8, lane);
  float qv = rs8(q8, lane);
  if ((lane >> 3) == jb) {
    sacc += sv;
    qacc += qv;
  }
}

__device__ __forceinline__ void block_combine_rc(float accS, float accQ,
                                                 float* __restrict__ sumg,
                                                 float* __restrict__ ssqg) {
  __shared__ float sS[256], sQ[256];
  sS[threadIdx.x] = accS;
  sQ[threadIdx.x] = accQ;
  __syncthreads();
  if (threadIdx.x < 64) {
    float S = sS[threadIdx.x] + sS[threadIdx.x + 64] + sS[threadIdx.x + 128] + sS[threadIdx.x + 192];
    float Q = sQ[threadIdx.x] + sQ[threadIdx.x + 64] + sQ[threadIdx.x + 128] + sQ[threadIdx.x + 192];
    atomicAdd(&sumg[threadIdx.x], S);
    atomicAdd(&ssqg[threadIdx.x], Q);
  }
}

// ---- P1: x second moments (shared) ---------------------------------------
__global__ void __launch_bounds__(256) k_stats_x(const float* __restrict__ x,
                                                 float* __restrict__ ws, int B) {
  int tid = blockIdx.x * 256 + threadIdx.x;
  int nt = gridDim.x * 256;
  float s0 = 0.f, s1 = 0.f, s2 = 0.f;
  float q00 = 0.f, q01 = 0.f, q02 = 0.f, q11 = 0.f, q12 = 0.f, q22 = 0.f;
  for (int r = tid; r < B; r += nt) {
    float x0 = x[3 * r], x1 = x[3 * r + 1], x2 = x[3 * r + 2];
    s0 += x0; s1 += x1; s2 += x2;
    q00 = fmaf(x0, x0, q00); q01 = fmaf(x0, x1, q01); q02 = fmaf(x0, x2, q02);
    q11 = fmaf(x1, x1, q11); q12 = fmaf(x1, x2, q12); q22 = fmaf(x2, x2, q22);
  }
  s0 = wred64(s0); s1 = wred64(s1); s2 = wred64(s2);
  q00 = wred64(q00); q01 = wred64(q01); q02 = wred64(q02);
  q11 = wred64(q11); q12 = wred64(q12); q22 = wred64(q22);
  __shared__ float part[9];
  if (threadIdx.x < 9) part[threadIdx.x] = 0.f;
  __syncthreads();
  if ((threadIdx.x & 63) == 0) {
    atomicAdd(&part[0], s0); atomicAdd(&part[1], s1); atomicAdd(&part[2], s2);
    atomicAdd(&part[3], q00); atomicAdd(&part[4], q01); atomicAdd(&part[5], q02);
    atomicAdd(&part[6], q11); atomicAdd(&part[7], q12); atomicAdd(&part[8], q22);
  }
  __syncthreads();
  if (threadIdx.x < 9) atomicAdd(&ws[WS_STAT9 + threadIdx.x], part[threadIdx.x]);
}

// ---- P2: fold BN1 (shared) ------------------------------------------------
__global__ void k_fin1(const float* __restrict__ W1, const float* __restrict__ b1,
                       const float* __restrict__ g1, const float* __restrict__ be1,
                       float* __restrict__ ws, int B) {
  int j = threadIdx.x;  // 64
  float inv = 1.0f / (float)B;
  float ex0 = ws[0] * inv, ex1 = ws[1] * inv, ex2 = ws[2] * inv;
  float c00 = ws[3] * inv - ex0 * ex0;
  float c01 = ws[4] * inv - ex0 * ex1;
  float c02 = ws[5] * inv - ex0 * ex2;
  float c11 = ws[6] * inv - ex1 * ex1;
  float c12 = ws[7] * inv - ex1 * ex2;
  float c22 = ws[8] * inv - ex2 * ex2;
  float w0 = W1[3 * j], w1 = W1[3 * j + 1], w2 = W1[3 * j + 2];
  float mean = w0 * ex0 + w1 * ex1 + w2 * ex2 + b1[j];
  float var = w0 * w0 * c00 + w1 * w1 * c11 + w2 * w2 * c22 +
              2.f * (w0 * w1 * c01 + w0 * w2 * c02 + w1 * w2 * c12);
  float s = g1[j] * rsqrtf(var + kEps);
  ws[WS_W1P + 3 * j + 0] = s * w0;
  ws[WS_W1P + 3 * j + 1] = s * w1;
  ws[WS_W1P + 3 * j + 2] = s * w2;
  ws[WS_C1 + j] = fmaf(s, b1[j] - mean, be1[j]);
}

// =========================== FAST PATH =====================================
// zbuf layout: 8 planes; plane jb is [B] x uint4, holding bf16 z-values for
// units jb*8 .. jb*8+7 of every row (low16 of word = even unit).
// Thread PAIRS (lane l even, l^1 odd) share row r = tid>>1 + it*npair;
// parity q = lane&1 owns k-half [32q, 32q+32).

// ---- P3: z2 = W2 h1 + b2 -> bf16 planes + fused BN2 stats ----------------
__global__ void HEAVY_BOUNDS k_z2(const float* __restrict__ x,
                                  const float* __restrict__ W2,
                                  const float* __restrict__ b2,
                                  float* __restrict__ ws,
                                  unsigned short* __restrict__ zb, int B) {
  const float* W1p = ws + WS_W1P;
  const float* c1 = ws + WS_C1;
  uint4* __restrict__ zp = (uint4*)zb;
  int tid = blockIdx.x * 256 + threadIdx.x;
  int nt = gridDim.x * 256;
  int lane = threadIdx.x & 63;
  int q = lane & 1;
  int npair = nt >> 1;
  float sacc = 0.f, qacc = 0.f;
  int iters = (B + npair - 1) / npair;
  for (int it = 0; it < iters; ++it) {
    int r = (tid >> 1) + it * npair;
    bool valid = (r < B);
    int rc = valid ? r : (B - 1);
    float w = (valid && q == 0) ? 1.f : 0.f;
    float x0 = x[3 * rc], x1 = x[3 * rc + 1], x2 = x[3 * rc + 2];
    float h[32];
    const float* Wq = W1p + 96 * q;
    const float* cq = c1 + 32 * q;
#pragma unroll
    for (int i = 0; i < 32; ++i) {
      float z = fmaf(Wq[3 * i + 2], x2,
                 fmaf(Wq[3 * i + 1], x1, fmaf(Wq[3 * i + 0], x0, cq[i])));
      h[i] = fmaxf(z, 0.f);
    }
#pragma unroll 1
    for (int jb = 0; jb < 8; ++jb) {
      float z[8];
#pragma unroll
      for (int u = 0; u < 8; ++u) {
        int j = jb * 8 + u;
        float p = dot32(W2 + j * 64 + 32 * q, h);
        z[u] = p + __shfl_xor(p, 1, 64) + b2[j];
      }
      stat_rs8s(z, jb, lane, w, sacc, qacc);
      if (valid && q == (jb >> 2)) {
        uint4 o;
        o.x = packbf2(z[0], z[1]); o.y = packbf2(z[2], z[3]);
        o.z = packbf2(z[4], z[5]); o.w = packbf2(z[6], z[7]);
        zp[(size_t)jb * B + r] = o;
      }
    }
  }
  block_combine_rc(sacc, qacc, ws + WS_SUM2, ws + WS_SSQ2);
}

// ---- P4/P6: BN scale/shift only ------------------------------------------
__global__ void k_fin_bn(const float* __restrict__ sum, const float* __restrict__ ssq,
                         const float* __restrict__ g, const float* __restrict__ be,
                         float* __restrict__ sOut, float* __restrict__ cOut, int B) {
  int j = threadIdx.x;  // 64
  float inv = 1.0f / (float)B;
  float mean = sum[j] * inv;
  float var = ssq[j] * inv - mean * mean;
  float s = g[j] * rsqrtf(var + kEps);
  sOut[j] = s;
  cOut[j] = fmaf(-s, mean, be[j]);
}

// ---- P5: z3 = W3 relu(s2*z2+c2) + b3, in place + fused BN3 stats ---------
__global__ void HEAVY_BOUNDS k_z3(const float* __restrict__ W3,
                                  const float* __restrict__ b3,
                                  float* __restrict__ ws,
                                  unsigned short* __restrict__ zb, int B) {
  const float* s2 = ws + FP_S2;
  const float* c2 = ws + FP_C2;
  uint4* __restrict__ zp = (uint4*)zb;
  int tid = blockIdx.x * 256 + threadIdx.x;
  int nt = gridDim.x * 256;
  int lane = threadIdx.x & 63;
  int q = lane & 1;
  int npair = nt >> 1;
  float sacc = 0.f, qacc = 0.f;
  int iters = (B + npair - 1) / npair;
  for (int it = 0; it < iters; ++it) {
    int r = (tid >> 1) + it * npair;
    bool valid = (r < B);
    int rc = valid ? r : (B - 1);
    float w = (valid && q == 0) ? 1.f : 0.f;
    float h[32];
#pragma unroll
    for (int o = 0; o < 4; ++o) {
      int p = 4 * q + o;          // plane
      int ub = 8 * p;             // global unit base = 32q + 8o
      uint4 v = zp[(size_t)p * B + rc];
      float a, b;
      unpack2(v.x, a, b);
      h[8 * o + 0] = fmaxf(fmaf(s2[ub + 0], a, c2[ub + 0]), 0.f);
      h[8 * o + 1] = fmaxf(fmaf(s2[ub + 1], b, c2[ub + 1]), 0.f);
      unpack2(v.y, a, b);
      h[8 * o + 2] = fmaxf(fmaf(s2[ub + 2], a, c2[ub + 2]), 0.f);
      h[8 * o + 3] = fmaxf(fmaf(s2[ub + 3], b, c2[ub + 3]), 0.f);
      unpack2(v.z, a, b);
      h[8 * o + 4] = fmaxf(fmaf(s2[ub + 4], a, c2[ub + 4]), 0.f);
      h[8 * o + 5] = fmaxf(fmaf(s2[ub + 5], b, c2[ub + 5]), 0.f);
      unpack2(v.w, a, b);
      h[8 * o + 6] = fmaxf(fmaf(s2[ub + 6], a, c2[ub + 6]), 0.f);
      h[8 * o + 7] = fmaxf(fmaf(s2[ub + 7], b, c2[ub + 7]), 0.f);
    }
#pragma unroll 1
    for (int jb = 0; jb < 8; ++jb) {
      float z[8];
#pragma unroll
      for (int u = 0; u < 8; ++u) {
        int j = jb * 8 + u;
        float p = dot32(W3 + j * 64 + 32 * q, h);
        z[u] = p + __shfl_xor(p, 1, 64) + b3[j];
      }
      stat_rs8s(z, jb, lane, w, sacc, qacc);
      if (valid && q == (jb >> 2)) {
        uint4 o;
        o.x = packbf2(z[0], z[1]); o.y = packbf2(z[2], z[3]);
        o.z = packbf2(z[4], z[5]); o.w = packbf2(z[6], z[7]);
        zp[(size_t)jb * B + r] = o;
      }
    }
  }
  block_combine_rc(sacc, qacc, ws + WS_SUM3, ws + WS_SSQ3);
}

// ---- P7: h3 -> head -> FK -> out (paired) --------------------------------
__global__ void HEAVY_BOUNDS k_final_fast(const unsigned short* __restrict__ zb,
                                          const float* __restrict__ W4,
                                          const float* __restrict__ b4,
                                          const float* __restrict__ ws,
                                          float* __restrict__ out, int B) {
  const float* s3 = ws + FP_S3;
  const float* c3 = ws + FP_C3;
  const uint4* __restrict__ zp = (const uint4*)zb;
  int tid = blockIdx.x * 256 + threadIdx.x;
  int nt = gridDim.x * 256;
  int lane = threadIdx.x & 63;
  int q = lane & 1;
  int npair = nt >> 1;
  int iters = (B + npair - 1) / npair;
  for (int it = 0; it < iters; ++it) {
    int r = (tid >> 1) + it * npair;
    bool valid = (r < B);
    int rc = valid ? r : (B - 1);
    float h[32];
#pragma unroll
    for (int o = 0; o < 4; ++o) {
      int p = 4 * q + o;
      int ub = 8 * p;
      uint4 v = zp[(size_t)p * B + rc];
      float a, b;
      unpack2(v.x, a, b);
      h[8 * o + 0] = fmaxf(fmaf(s3[ub + 0], a, c3[ub + 0]), 0.f);
      h[8 * o + 1] = fmaxf(fmaf(s3[ub + 1], b, c3[ub + 1]), 0.f);
      unpack2(v.y, a, b);
      h[8 * o + 2] = fmaxf(fmaf(s3[ub + 2], a, c3[ub + 2]), 0.f);
      h[8 * o + 3] = fmaxf(fmaf(s3[ub + 3], b, c3[ub + 3]), 0.f);
      unpack2(v.z, a, b);
      h[8 * o + 4] = fmaxf(fmaf(s3[ub + 4], a, c3[ub + 4]), 0.f);
      h[8 * o + 5] = fmaxf(fmaf(s3[ub + 5], b, c3[ub + 5]), 0.f);
      unpack2(v.w, a, b);
      h[8 * o + 6] = fmaxf(fmaf(s3[ub + 6], a, c3[ub + 6]), 0.f);
      h[8 * o + 7] = fmaxf(fmaf(s3[ub + 7], b, c3[ub + 7]), 0.f);
    }
    float p0 = dot32(W4 + 32 * q, h);
    float p1 = dot32(W4 + 64 + 32 * q, h);
    float p2 = dot32(W4 + 128 + 32 * q, h);
    float t0 = p0 + __shfl_xor(p0, 1, 64) + b4[0];
    float t1 = p1 + __shfl_xor(p1, 1, 64) + b4[1];
    float t2 = p2 + __shfl_xor(p2, 1, 64) + b4[2];
    if (valid) {
      if (q == 0) {
        out[3 * r + 0] = t0;
        out[3 * r + 1] = t1;
        out[3 * r + 2] = t2;
      } else {
        float s0, c0v, s1, c1v, s12, c12;
        sincosf(t0, &s0, &c0v);
        sincosf(t1, &s1, &c1v);
        sincosf(t1 + t2, &s12, &c12);
        float A = fmaf(0.115f, c12, 0.12f * c1v);
        size_t o2 = (size_t)3 * B + 3 * r;
        out[o2 + 0] = c0v * A;
        out[o2 + 1] = s0 * A;
        out[o2 + 2] = fmaf(0.115f, s12, 0.12f * s1);
      }
    }
  }
}

// ========================= FALLBACK (R1, verified) =========================

__device__ __forceinline__ void layer1_eval(const float* __restrict__ W1p,
                                            const float* __restrict__ c1,
                                            float x0, float x1, float x2,
                                            float h[64]) {
#pragma unroll
  for (int j = 0; j < 64; ++j) {
    float z = fmaf(W1p[3 * j + 2], x2,
               fmaf(W1p[3 * j + 1], x1, fmaf(W1p[3 * j], x0, c1[j])));
    h[j] = fmaxf(z, 0.f);
  }
}

__device__ __forceinline__ void dense_relu_rc(const float* __restrict__ Wp,
                                              const float* __restrict__ c,
                                              const float hin[64], float hout[64]) {
#pragma unroll
  for (int j = 0; j < 64; ++j)
    hout[j] = fmaxf(dot64(Wp + j * 64, hin) + c[j], 0.f);
}

__device__ __forceinline__ void dense_stats_rc(const float* __restrict__ W,
                                               const float* __restrict__ b,
                                               const float hin[64], int lane,
                                               float valid, float& accS, float& accQ) {
#pragma unroll 1
  for (int j = 0; j < 64; ++j) {
    float z = (dot64(W + j * 64, hin) + b[j]) * valid;
    float rs = wred64(z);
    float rq = wred64(z * z);
    accS += (lane == j) ? rs : 0.f;
    accQ += (lane == j) ? rq : 0.f;
  }
}

__global__ void __launch_bounds__(256) k_stats2_rc(const float* __restrict__ x,
                                                   const float* __restrict__ W2,
                                                   const float* __restrict__ b2,
                                                   float* __restrict__ ws, int B) {
  const float* W1p = ws + WS_W1P;
  const float* c1 = ws + WS_C1;
  int tid = blockIdx.x * 256 + threadIdx.x;
  int nt = gridDim.x * 256;
  int lane = threadIdx.x & 63;
  float accS = 0.f, accQ = 0.f;
  int iters = (B + nt - 1) / nt;
  for (int it = 0; it < iters; ++it) {
    int r = tid + it * nt;
    float valid = (r < B) ? 1.f : 0.f;
    int rc = (r < B) ? r : (B - 1);
    float h1[64];
    layer1_eval(W1p, c1, x[3 * rc], x[3 * rc + 1], x[3 * rc + 2], h1);
    dense_stats_rc(W2, b2, h1, lane, valid, accS, accQ);
  }
  block_combine_rc(accS, accQ, ws + WS_SUM2, ws + WS_SSQ2);
}

__global__ void k_fin_dense_rc(const float* __restrict__ W, const float* __restrict__ b,
                               const float* __restrict__ g, const float* __restrict__ be,
                               const float* __restrict__ sum, const float* __restrict__ ssq,
                               float* __restrict__ Wp, float* __restrict__ cc, int B) {
  int j = threadIdx.x;
  float inv = 1.0f / (float)B;
  float mean = sum[j] * inv;
  float var = ssq[j] * inv - mean * mean;
  float s = g[j] * rsqrtf(var + kEps);
  for (int k = 0; k < 64; ++k) Wp[j * 64 + k] = s * W[j * 64 + k];
  cc[j] = fmaf(s, b[j] - mean, be[j]);
}

__global__ void __launch_bounds__(256) k_stats3_rc(const float* __restrict__ x,
                                                   const float* __restrict__ W3,
                                                   const float* __restrict__ b3,
                                                   float* __restrict__ ws, int B) {
  const float* W1p = ws + WS_W1P;
  const float* c1 = ws + WS_C1;
  const float* W2p = ws + RC_W2P;
  const float* c2 = ws + RC_C2;
  int tid = blockIdx.x * 256 + threadIdx.x;
  int nt = gridDim.x * 256;
  int lane = threadIdx.x & 63;
  float accS = 0.f, accQ = 0.f;
  int iters = (B + nt - 1) / nt;
  for (int it = 0; it < iters; ++it) {
    int r = tid + it * nt;
    float valid = (r < B) ? 1.f : 0.f;
    int rc = (r < B) ? r : (B - 1);
    float h1[64], h2[64];
    layer1_eval(W1p, c1, x[3 * rc], x[3 * rc + 1], x[3 * rc + 2], h1);
    dense_relu_rc(W2p, c2, h1, h2);
    dense_stats_rc(W3, b3, h2, lane, valid, accS, accQ);
  }
  block_combine_rc(accS, accQ, ws + WS_SUM3, ws + WS_SSQ3);
}

__global__ void __launch_bounds__(256) k_final_rc(const float* __restrict__ x,
                                                  const float* __restrict__ W4,
                                                  const float* __restrict__ b4,
                                                  const float* __restrict__ ws,
                                                  float* __restrict__ out, int B) {
  const float* W1p = ws + WS_W1P;
  const float* c1 = ws + WS_C1;
  const float* W2p = ws + RC_W2P;
  const float* c2 = ws + RC_C2;
  const float* W3p = ws + RC_W3P;
  const float* c3 = ws + RC_C3;
  int tid = blockIdx.x * 256 + threadIdx.x;
  int nt = gridDim.x * 256;
  for (int r = tid; r < B; r += nt) {
    float h1[64], h2[64];
    layer1_eval(W1p, c1, x[3 * r], x[3 * r + 1], x[3 * r + 2], h1);
    dense_relu_rc(W2p, c2, h1, h2);
    float t0 = b4[0], t1 = b4[1], t2 = b4[2];
#pragma unroll 1
    for (int j = 0; j < 64; ++j) {
      float h3 = fmaxf(dot64(W3p + j * 64, h2) + c3[j], 0.f);
      t0 = fmaf(W4[j], h3, t0);
      t1 = fmaf(W4[64 + j], h3, t1);
      t2 = fmaf(W4[128 + j], h3, t2);
    }
    out[3 * r + 0] = t0;
    out[3 * r + 1] = t1;
    out[3 * r + 2] = t2;
    float s0, c0v, s1, c1v, s12, c12;
    sincosf(t0, &s0, &c0v);
    sincosf(t1, &s1, &c1v);
    sincosf(t1 + t2, &s12, &c12);
    float A = fmaf(0.115f, c12, 0.12f * c1v);
    size_t o2 = (size_t)3 * B + 3 * r;
    out[o2 + 0] = c0v * A;
    out[o2 + 1] = s0 * A;
    out[o2 + 2] = fmaf(0.115f, s12, 0.12f * s1);
  }
}

// ===========================================================================

extern "C" void kernel_launch(void* const* d_in, const int* in_sizes, int n_in,
                              void* d_out, int out_size, void* d_ws, size_t ws_size,
                              hipStream_t stream) {
  const float* x = (const float*)d_in[0];
  const float* W1 = (const float*)d_in[1];
  const float* b1 = (const float*)d_in[2];
  const float* g1 = (const float*)d_in[3];
  const float* be1 = (const float*)d_in[4];
  const float* W2 = (const float*)d_in[5];
  const float* b2 = (const float*)d_in[6];
  const float* g2 = (const float*)d_in[7];
  const float* be2 = (const float*)d_in[8];
  const float* W3 = (const float*)d_in[9];
  const float* b3 = (const float*)d_in[10];
  const float* g3 = (const float*)d_in[11];
  const float* be3 = (const float*)d_in[12];
  const float* W4 = (const float*)d_in[13];
  const float* b4 = (const float*)d_in[14];
  float* ws = (float*)d_ws;
  float* out = (float*)d_out;
  int B = in_sizes[0] / 3;

  hipMemsetAsync(d_ws, 0, 272 * sizeof(float), stream);

  const int blocks = 1024, thr = 256;
  const int zblocks = 2048;
  size_t need = 65536 + (size_t)B * 64 * 2;

  k_stats_x<<<blocks, thr, 0, stream>>>(x, ws, B);
  k_fin1<<<1, 64, 0, stream>>>(W1, b1, g1, be1, ws, B);

  if (ws_size >= need) {
    unsigned short* zb = (unsigned short*)ws + ZB_U16;
    k_z2<<<zblocks, thr, 0, stream>>>(x, W2, b2, ws, zb, B);
    k_fin_bn<<<1, 64, 0, stream>>>(ws + WS_SUM2, ws + WS_SSQ2, g2, be2,
                                   ws + FP_S2, ws + FP_C2, B);
    k_z3<<<zblocks, thr, 0, stream>>>(W3, b3, ws, zb, B);
    k_fin_bn<<<1, 64, 0, stream>>>(ws + WS_SUM3, ws + WS_SSQ3, g3, be3,
                                   ws + FP_S3, ws + FP_C3, B);
    k_final_fast<<<zblocks, thr, 0, stream>>>(zb, W4, b4, ws, out, B);
  } else {
    k_stats2_rc<<<blocks, thr, 0, stream>>>(x, W2, b2, ws, B);
    k_fin_dense_rc<<<1, 64, 0, stream>>>(W2, b2, g2, be2, ws + WS_SUM2, ws + WS_SSQ2,
                                         ws + RC_W2P, ws + RC_C2, B);
    k_stats3_rc<<<blocks, thr, 0, stream>>>(x, W3, b3, ws, B);
    k_fin_dense_rc<<<1, 64, 0, stream>>>(W3, b3, g3, be3, ws + WS_SUM3, ws + WS_SSQ3,
                                         ws + RC_W3P, ws + RC_C3, B);
    k_final_rc<<<blocks, thr, 0, stream>>>(x, W4, b4, ws, out, B);
  }
}

// Round 11
// 1215.348 us; speedup vs baseline: 1.8868x; 1.8868x over previous
//
#include <hip/hip_runtime.h>
#include <math.h>

// ---------------------------------------------------------------------------
// InvKin (R18): R17's vmcnt-domain weight loads, with the launder fixed.
// R17 post-mortem: divptr's two v_mov_b32 with plain "=v" outputs let the
// allocator alias output %0 with input %3 -> first mov clobbered hi before
// the second read it -> corrupted pointer -> device fault (the classic
// missing-early-clobber trap). The experiment never ran.
// R18: launder via EMPTY asm with "+v" tie constraints — input/output
// share a register by construction (no hazard, zero instructions), and
// the asm output is opaque to uniformity analysis, so weight addressing
// still emits global_load_dwordx4 (vmcnt domain) instead of s_load
// (lgkmcnt, shared with rs8's DS shuffles). Hypothesis unchanged: R11's
// wall ~2.3x VALU-busy is the shuffle lgkmcnt(0) draining the s_load
// weight prefetch queue every jb block; decoupling the counters lets
// weight prefetch survive stats. W is 16KB -> L1-resident; uniform addr
// -> one L1 transaction + broadcast. FMA association unchanged -> absmax
// bit-identical to R11. Everything else exactly R11 (489us PASS).
//   P1 k_stats_x   P2 k_fin1   P3 k_z2 (fused BN2 stats)   P4 k_fin_bn
//   P5 k_z3 (in place, fused BN3 stats)   P6 k_fin_bn   P7 k_final
// Fallback path (small ws): exact R1 kernel set (verified PASS).
// ---------------------------------------------------------------------------

static constexpr float kEps = 1e-5f;

#define HEAVY_BOUNDS __launch_bounds__(256) __attribute__((amdgpu_waves_per_eu(3, 4)))

// shared ws fp32 indices (both paths)
#define WS_STAT9 0
#define WS_SUM2  16
#define WS_SSQ2  80
#define WS_SUM3  144
#define WS_SSQ3  208
#define WS_W1P   288    // [64][3] fp32 (BN1-folded)
#define WS_C1    480    // [64]
// fast path only
#define FP_S2    8192
#define FP_C2    8256
#define FP_S3    8320
#define FP_C3    8384
// fallback (R1) only — may overlap FP_* since only one path ever runs
#define RC_W2P   544
#define RC_C2    4640
#define RC_W3P   4704
#define RC_C3    8800
// z buffer: byte offset 65536 (ushort index 32768)
#define ZB_U16   32768

// packed bf16x2 convert, round-to-nearest-even
__device__ __forceinline__ unsigned packbf2(float a, float b) {
  unsigned r;
  asm("v_cvt_pk_bf16_f32 %0, %1, %2" : "=v"(r) : "v"(a), "v"(b));
  return r;
}
__device__ __forceinline__ void unpack2(unsigned w, float& lo, float& hi) {
  lo = __builtin_bit_cast(float, w << 16);
  hi = __builtin_bit_cast(float, w & 0xffff0000u);
}

// launder a pointer into VGPRs: empty asm with "+v" ties (no instructions,
// no aliasing hazard); the result is opaque to uniformity analysis, so
// addressing off it emits vector global_loads (vmcnt) instead of s_loads
// (lgkmcnt, which rs8's DS shuffles would drain).
__device__ __forceinline__ const float* divptr(const float* p) {
  unsigned long long u = (unsigned long long)p;
  unsigned lo = (unsigned)u, hi = (unsigned)(u >> 32);
  asm("" : "+v"(lo), "+v"(hi));
  return (const float*)(((unsigned long long)hi << 32) | (unsigned long long)lo);
}

__device__ __forceinline__ float wred64(float v) {
  v += __shfl_xor(v, 32, 64);
  v += __shfl_xor(v, 16, 64);
  v += __shfl_xor(v, 8, 64);
  v += __shfl_xor(v, 4, 64);
  v += __shfl_xor(v, 2, 64);
  v += __shfl_xor(v, 1, 64);
  return v;
}

// butterfly reduce-scatter over 8 values: returns the full 64-lane sum of
// v[lane&7]. Levels 1/2/4 reduce-scatter the 8 units across the 8-lane
// group; levels 8/16/32 all-reduce the survivor across the 8 groups.
__device__ __forceinline__ float rs8(const float* v, int lane) {
  int b0 = lane & 1, b1 = (lane >> 1) & 1, b2 = (lane >> 2) & 1;
  float r[4];
#pragma unroll
  for (int i = 0; i < 4; ++i) {
    float keep = b0 ? v[2 * i + 1] : v[2 * i];
    float send = b0 ? v[2 * i] : v[2 * i + 1];
    r[i] = keep + __shfl_xor(send, 1, 64);
  }
  float t[2];
#pragma unroll
  for (int i = 0; i < 2; ++i) {
    float keep = b1 ? r[2 * i + 1] : r[2 * i];
    float send = b1 ? r[2 * i] : r[2 * i + 1];
    t[i] = keep + __shfl_xor(send, 2, 64);
  }
  float keep = b2 ? t[1] : t[0];
  float send = b2 ? t[0] : t[1];
  float u = keep + __shfl_xor(send, 4, 64);
  u += __shfl_xor(u, 8, 64);
  u += __shfl_xor(u, 16, 64);
  u += __shfl_xor(u, 32, 64);
  return u;
}

// dot over 64 k via float4 vector loads (base must be divptr'd).
// Same 4-accumulator association as the scalar dot64.
__device__ __forceinline__ float dot64f4(const float* __restrict__ wr,
                                         const float hin[64]) {
  const float4* w4 = (const float4*)wr;
  float a0 = 0.f, a1 = 0.f, a2 = 0.f, a3 = 0.f;
#pragma unroll
  for (int k = 0; k < 16; ++k) {
    float4 w = w4[k];
    a0 = fmaf(w.x, hin[4 * k + 0], a0);
    a1 = fmaf(w.y, hin[4 * k + 1], a1);
    a2 = fmaf(w.z, hin[4 * k + 2], a2);
    a3 = fmaf(w.w, hin[4 * k + 3], a3);
  }
  return (a0 + a1) + (a2 + a3);
}

__device__ __forceinline__ float dot64(const float* __restrict__ wr,
                                       const float hin[64]) {
  float a0 = 0.f, a1 = 0.f, a2 = 0.f, a3 = 0.f;
#pragma unroll
  for (int k = 0; k < 64; k += 4) {
    a0 = fmaf(wr[k + 0], hin[k + 0], a0);
    a1 = fmaf(wr[k + 1], hin[k + 1], a1);
    a2 = fmaf(wr[k + 2], hin[k + 2], a2);
    a3 = fmaf(wr[k + 3], hin[k + 3], a3);
  }
  return (a0 + a1) + (a2 + a3);
}

// fused BN stats for one jb-block of 8 units, scalar-z form.
// lane l accumulates global unit (l>>3)*8 + (l&7) == l  (identity map).
__device__ __forceinline__ void stat_rs8s(const float* __restrict__ z, int jb,
                                          int lane, float w,
                                          float& sacc, float& qacc) {
  float s8[8], q8[8];
#pragma unroll
  for (int u = 0; u < 8; ++u) {
    s8[u] = w * z[u];
    q8[u] = s8[u] * z[u];
  }
  float sv = rs8(s8, lane);
  float qv = rs8(q8, lane);
  if ((lane >> 3) == jb) {
    sacc += sv;
    qacc += qv;
  }
}

__device__ __forceinline__ void block_combine_rc(float accS, float accQ,
                                                 float* __restrict__ sumg,
                                                 float* __restrict__ ssqg) {
  __shared__ float sS[256], sQ[256];
  sS[threadIdx.x] = accS;
  sQ[threadIdx.x] = accQ;
  __syncthreads();
  if (threadIdx.x < 64) {
    float S = sS[threadIdx.x] + sS[threadIdx.x + 64] + sS[threadIdx.x + 128] + sS[threadIdx.x + 192];
    float Q = sQ[threadIdx.x] + sQ[threadIdx.x + 64] + sQ[threadIdx.x + 128] + sQ[threadIdx.x + 192];
    atomicAdd(&sumg[threadIdx.x], S);
    atomicAdd(&ssqg[threadIdx.x], Q);
  }
}

// ---- P1: x second moments (shared) ---------------------------------------
__global__ void __launch_bounds__(256) k_stats_x(const float* __restrict__ x,
                                                 float* __restrict__ ws, int B) {
  int tid = blockIdx.x * 256 + threadIdx.x;
  int nt = gridDim.x * 256;
  float s0 = 0.f, s1 = 0.f, s2 = 0.f;
  float q00 = 0.f, q01 = 0.f, q02 = 0.f, q11 = 0.f, q12 = 0.f, q22 = 0.f;
  for (int r = tid; r < B; r += nt) {
    float x0 = x[3 * r], x1 = x[3 * r + 1], x2 = x[3 * r + 2];
    s0 += x0; s1 += x1; s2 += x2;
    q00 = fmaf(x0, x0, q00); q01 = fmaf(x0, x1, q01); q02 = fmaf(x0, x2, q02);
    q11 = fmaf(x1, x1, q11); q12 = fmaf(x1, x2, q12); q22 = fmaf(x2, x2, q22);
  }
  s0 = wred64(s0); s1 = wred64(s1); s2 = wred64(s2);
  q00 = wred64(q00); q01 = wred64(q01); q02 = wred64(q02);
  q11 = wred64(q11); q12 = wred64(q12); q22 = wred64(q22);
  __shared__ float part[9];
  if (threadIdx.x < 9) part[threadIdx.x] = 0.f;
  __syncthreads();
  if ((threadIdx.x & 63) == 0) {
    atomicAdd(&part[0], s0); atomicAdd(&part[1], s1); atomicAdd(&part[2], s2);
    atomicAdd(&part[3], q00); atomicAdd(&part[4], q01); atomicAdd(&part[5], q02);
    atomicAdd(&part[6], q11); atomicAdd(&part[7], q12); atomicAdd(&part[8], q22);
  }
  __syncthreads();
  if (threadIdx.x < 9) atomicAdd(&ws[WS_STAT9 + threadIdx.x], part[threadIdx.x]);
}

// ---- P2: fold BN1 (shared) ------------------------------------------------
__global__ void k_fin1(const float* __restrict__ W1, const float* __restrict__ b1,
                       const float* __restrict__ g1, const float* __restrict__ be1,
                       float* __restrict__ ws, int B) {
  int j = threadIdx.x;  // 64
  float inv = 1.0f / (float)B;
  float ex0 = ws[0] * inv, ex1 = ws[1] * inv, ex2 = ws[2] * inv;
  float c00 = ws[3] * inv - ex0 * ex0;
  float c01 = ws[4] * inv - ex0 * ex1;
  float c02 = ws[5] * inv - ex0 * ex2;
  float c11 = ws[6] * inv - ex1 * ex1;
  float c12 = ws[7] * inv - ex1 * ex2;
  float c22 = ws[8] * inv - ex2 * ex2;
  float w0 = W1[3 * j], w1 = W1[3 * j + 1], w2 = W1[3 * j + 2];
  float mean = w0 * ex0 + w1 * ex1 + w2 * ex2 + b1[j];
  float var = w0 * w0 * c00 + w1 * w1 * c11 + w2 * w2 * c22 +
              2.f * (w0 * w1 * c01 + w0 * w2 * c02 + w1 * w2 * c12);
  float s = g1[j] * rsqrtf(var + kEps);
  ws[WS_W1P + 3 * j + 0] = s * w0;
  ws[WS_W1P + 3 * j + 1] = s * w1;
  ws[WS_W1P + 3 * j + 2] = s * w2;
  ws[WS_C1 + j] = fmaf(s, b1[j] - mean, be1[j]);
}

// =========================== FAST PATH =====================================
// zbuf layout: 8 planes; plane jb is [B] x uint4, holding bf16 z-values for
// units jb*8 .. jb*8+7 of every row (low16 of word = even unit).
// Single row per thread; plane accesses are 64-consecutive-lane x 16B.

// ---- P3: z2 = W2 h1 + b2 -> bf16 planes + fused BN2 stats ----------------
__global__ void HEAVY_BOUNDS k_z2(const float* __restrict__ x,
                                  const float* __restrict__ W2,
                                  const float* __restrict__ b2,
                                  float* __restrict__ ws,
                                  unsigned short* __restrict__ zb, int B) {
  const float* W1p = ws + WS_W1P;
  const float* c1 = ws + WS_C1;
  const float* W2d = divptr(W2);   // weight reads -> vmcnt domain
  uint4* __restrict__ zp = (uint4*)zb;
  int tid = blockIdx.x * 256 + threadIdx.x;
  int nt = gridDim.x * 256;
  int lane = threadIdx.x & 63;
  float sacc = 0.f, qacc = 0.f;
  int iters = (B + nt - 1) / nt;
  for (int it = 0; it < iters; ++it) {
    int r = tid + it * nt;
    bool valid = (r < B);
    int rc = valid ? r : (B - 1);
    float w = valid ? 1.f : 0.f;
    float x0 = x[3 * rc], x1 = x[3 * rc + 1], x2 = x[3 * rc + 2];
    float h[64];
#pragma unroll
    for (int k = 0; k < 64; ++k) {
      float z = fmaf(W1p[3 * k + 2], x2,
                 fmaf(W1p[3 * k + 1], x1, fmaf(W1p[3 * k], x0, c1[k])));
      h[k] = fmaxf(z, 0.f);
    }
#pragma unroll 1
    for (int jb = 0; jb < 8; ++jb) {
      float z[8];
#pragma unroll
      for (int u = 0; u < 8; ++u) {
        int j = jb * 8 + u;
        z[u] = dot64f4(W2d + j * 64, h) + b2[j];
      }
      stat_rs8s(z, jb, lane, w, sacc, qacc);
      if (valid) {
        uint4 o;
        o.x = packbf2(z[0], z[1]); o.y = packbf2(z[2], z[3]);
        o.z = packbf2(z[4], z[5]); o.w = packbf2(z[6], z[7]);
        zp[(size_t)jb * B + r] = o;
      }
    }
  }
  block_combine_rc(sacc, qacc, ws + WS_SUM2, ws + WS_SSQ2);
}

// ---- P4/P6: BN scale/shift only ------------------------------------------
__global__ void k_fin_bn(const float* __restrict__ sum, const float* __restrict__ ssq,
                         const float* __restrict__ g, const float* __restrict__ be,
                         float* __restrict__ sOut, float* __restrict__ cOut, int B) {
  int j = threadIdx.x;  // 64
  float inv = 1.0f / (float)B;
  float mean = sum[j] * inv;
  float var = ssq[j] * inv - mean * mean;
  float s = g[j] * rsqrtf(var + kEps);
  sOut[j] = s;
  cOut[j] = fmaf(-s, mean, be[j]);
}

// ---- P5: z3 = W3 relu(s2*z2+c2) + b3, in place + fused BN3 stats ---------
__global__ void HEAVY_BOUNDS k_z3(const float* __restrict__ W3,
                                  const float* __restrict__ b3,
                                  float* __restrict__ ws,
                                  unsigned short* __restrict__ zb, int B) {
  const float* s2 = ws + FP_S2;
  const float* c2 = ws + FP_C2;
  const float* W3d = divptr(W3);   // weight reads -> vmcnt domain
  uint4* __restrict__ zp = (uint4*)zb;
  int tid = blockIdx.x * 256 + threadIdx.x;
  int nt = gridDim.x * 256;
  int lane = threadIdx.x & 63;
  float sacc = 0.f, qacc = 0.f;
  int iters = (B + nt - 1) / nt;
  for (int it = 0; it < iters; ++it) {
    int r = tid + it * nt;
    bool valid = (r < B);
    int rc = valid ? r : (B - 1);
    float w = valid ? 1.f : 0.f;
    float h[64];
#pragma unroll
    for (int o = 0; o < 8; ++o) {
      uint4 v = zp[(size_t)o * B + rc];
      float a, b;
      unpack2(v.x, a, b);
      h[8 * o + 0] = fmaxf(fmaf(s2[8 * o + 0], a, c2[8 * o + 0]), 0.f);
      h[8 * o + 1] = fmaxf(fmaf(s2[8 * o + 1], b, c2[8 * o + 1]), 0.f);
      unpack2(v.y, a, b);
      h[8 * o + 2] = fmaxf(fmaf(s2[8 * o + 2], a, c2[8 * o + 2]), 0.f);
      h[8 * o + 3] = fmaxf(fmaf(s2[8 * o + 3], b, c2[8 * o + 3]), 0.f);
      unpack2(v.z, a, b);
      h[8 * o + 4] = fmaxf(fmaf(s2[8 * o + 4], a, c2[8 * o + 4]), 0.f);
      h[8 * o + 5] = fmaxf(fmaf(s2[8 * o + 5], b, c2[8 * o + 5]), 0.f);
      unpack2(v.w, a, b);
      h[8 * o + 6] = fmaxf(fmaf(s2[8 * o + 6], a, c2[8 * o + 6]), 0.f);
      h[8 * o + 7] = fmaxf(fmaf(s2[8 * o + 7], b, c2[8 * o + 7]), 0.f);
    }
#pragma unroll 1
    for (int jb = 0; jb < 8; ++jb) {
      float z[8];
#pragma unroll
      for (int u = 0; u < 8; ++u) {
        int j = jb * 8 + u;
        z[u] = dot64f4(W3d + j * 64, h) + b3[j];
      }
      stat_rs8s(z, jb, lane, w, sacc, qacc);
      if (valid) {
        uint4 o;
        o.x = packbf2(z[0], z[1]); o.y = packbf2(z[2], z[3]);
        o.z = packbf2(z[4], z[5]); o.w = packbf2(z[6], z[7]);
        zp[(size_t)jb * B + r] = o;
      }
    }
  }
  block_combine_rc(sacc, qacc, ws + WS_SUM3, ws + WS_SSQ3);
}

// ---- P7: h3 -> head -> FK -> out -----------------------------------------
__global__ void HEAVY_BOUNDS k_final_fast(const unsigned short* __restrict__ zb,
                                          const float* __restrict__ W4,
                                          const float* __restrict__ b4,
                                          const float* __restrict__ ws,
                                          float* __restrict__ out, int B) {
  const float* s3 = ws + FP_S3;
  const float* c3 = ws + FP_C3;
  const float* W4d = divptr(W4);
  const uint4* __restrict__ zp = (const uint4*)zb;
  int tid = blockIdx.x * 256 + threadIdx.x;
  int nt = gridDim.x * 256;
  for (int r = tid; r < B; r += nt) {
    float h[64];
#pragma unroll
    for (int jb = 0; jb < 8; ++jb) {
      uint4 v = zp[(size_t)jb * B + r];
      unpack2(v.x, h[jb * 8 + 0], h[jb * 8 + 1]);
      unpack2(v.y, h[jb * 8 + 2], h[jb * 8 + 3]);
      unpack2(v.z, h[jb * 8 + 4], h[jb * 8 + 5]);
      unpack2(v.w, h[jb * 8 + 6], h[jb * 8 + 7]);
    }
#pragma unroll
    for (int k = 0; k < 64; ++k)
      h[k] = fmaxf(fmaf(s3[k], h[k], c3[k]), 0.f);
    float t0 = dot64f4(W4d, h) + b4[0];
    float t1 = dot64f4(W4d + 64, h) + b4[1];
    float t2 = dot64f4(W4d + 128, h) + b4[2];
    out[3 * r + 0] = t0;
    out[3 * r + 1] = t1;
    out[3 * r + 2] = t2;
    float s0, c0v, s1, c1v, s12, c12;
    sincosf(t0, &s0, &c0v);
    sincosf(t1, &s1, &c1v);
    sincosf(t1 + t2, &s12, &c12);
    float A = fmaf(0.115f, c12, 0.12f * c1v);
    size_t o2 = (size_t)3 * B + 3 * r;
    out[o2 + 0] = c0v * A;
    out[o2 + 1] = s0 * A;
    out[o2 + 2] = fmaf(0.115f, s12, 0.12f * s1);
  }
}

// ========================= FALLBACK (R1, verified) =========================

__device__ __forceinline__ void layer1_eval(const float* __restrict__ W1p,
                                            const float* __restrict__ c1,
                                            float x0, float x1, float x2,
                                            float h[64]) {
#pragma unroll
  for (int j = 0; j < 64; ++j) {
    float z = fmaf(W1p[3 * j + 2], x2,
               fmaf(W1p[3 * j + 1], x1, fmaf(W1p[3 * j], x0, c1[j])));
    h[j] = fmaxf(z, 0.f);
  }
}

__device__ __forceinline__ void dense_relu_rc(const float* __restrict__ Wp,
                                              const float* __restrict__ c,
                                              const float hin[64], float hout[64]) {
#pragma unroll
  for (int j = 0; j < 64; ++j)
    hout[j] = fmaxf(dot64(Wp + j * 64, hin) + c[j], 0.f);
}

__device__ __forceinline__ void dense_stats_rc(const float* __restrict__ W,
                                               const float* __restrict__ b,
                                               const float hin[64], int lane,
                                               float valid, float& accS, float& accQ) {
#pragma unroll 1
  for (int j = 0; j < 64; ++j) {
    float z = (dot64(W + j * 64, hin) + b[j]) * valid;
    float rs = wred64(z);
    float rq = wred64(z * z);
    accS += (lane == j) ? rs : 0.f;
    accQ += (lane == j) ? rq : 0.f;
  }
}

__global__ void __launch_bounds__(256) k_stats2_rc(const float* __restrict__ x,
                                                   const float* __restrict__ W2,
                                                   const float* __restrict__ b2,
                                                   float* __restrict__ ws, int B) {
  const float* W1p = ws + WS_W1P;
  const float* c1 = ws + WS_C1;
  int tid = blockIdx.x * 256 + threadIdx.x;
  int nt = gridDim.x * 256;
  int lane = threadIdx.x & 63;
  float accS = 0.f, accQ = 0.f;
  int iters = (B + nt - 1) / nt;
  for (int it = 0; it < iters; ++it) {
    int r = tid + it * nt;
    float valid = (r < B) ? 1.f : 0.f;
    int rc = (r < B) ? r : (B - 1);
    float h1[64];
    layer1_eval(W1p, c1, x[3 * rc], x[3 * rc + 1], x[3 * rc + 2], h1);
    dense_stats_rc(W2, b2, h1, lane, valid, accS, accQ);
  }
  block_combine_rc(accS, accQ, ws + WS_SUM2, ws + WS_SSQ2);
}

__global__ void k_fin_dense_rc(const float* __restrict__ W, const float* __restrict__ b,
                               const float* __restrict__ g, const float* __restrict__ be,
                               const float* __restrict__ sum, const float* __restrict__ ssq,
                               float* __restrict__ Wp, float* __restrict__ cc, int B) {
  int j = threadIdx.x;
  float inv = 1.0f / (float)B;
  float mean = sum[j] * inv;
  float var = ssq[j] * inv - mean * mean;
  float s = g[j] * rsqrtf(var + kEps);
  for (int k = 0; k < 64; ++k) Wp[j * 64 + k] = s * W[j * 64 + k];
  cc[j] = fmaf(s, b[j] - mean, be[j]);
}

__global__ void __launch_bounds__(256) k_stats3_rc(const float* __restrict__ x,
                                                   const float* __restrict__ W3,
                                                   const float* __restrict__ b3,
                                                   float* __restrict__ ws, int B) {
  const float* W1p = ws + WS_W1P;
  const float* c1 = ws + WS_C1;
  const float* W2p = ws + RC_W2P;
  const float* c2 = ws + RC_C2;
  int tid = blockIdx.x * 256 + threadIdx.x;
  int nt = gridDim.x * 256;
  int lane = threadIdx.x & 63;
  float accS = 0.f, accQ = 0.f;
  int iters = (B + nt - 1) / nt;
  for (int it = 0; it < iters; ++it) {
    int r = tid + it * nt;
    float valid = (r < B) ? 1.f : 0.f;
    int rc = (r < B) ? r : (B - 1);
    float h1[64], h2[64];
    layer1_eval(W1p, c1, x[3 * rc], x[3 * rc + 1], x[3 * rc + 2], h1);
    dense_relu_rc(W2p, c2, h1, h2);
    dense_stats_rc(W3, b3, h2, lane, valid, accS, accQ);
  }
  block_combine_rc(accS, accQ, ws + WS_SUM3, ws + WS_SSQ3);
}

__global__ void __launch_bounds__(256) k_final_rc(const float* __restrict__ x,
                                                  const float* __restrict__ W4,
                                                  const float* __restrict__ b4,
                                                  const float* __restrict__ ws,
                                                  float* __restrict__ out, int B) {
  const float* W1p = ws + WS_W1P;
  const float* c1 = ws + WS_C1;
  const float* W2p = ws + RC_W2P;
  const float* c2 = ws + RC_C2;
  const float* W3p = ws + RC_W3P;
  const float* c3 = ws + RC_C3;
  int tid = blockIdx.x * 256 + threadIdx.x;
  int nt = gridDim.x * 256;
  for (int r = tid; r < B; r += nt) {
    float h1[64], h2[64];
    layer1_eval(W1p, c1, x[3 * r], x[3 * r + 1], x[3 * r + 2], h1);
    dense_relu_rc(W2p, c2, h1, h2);
    float t0 = b4[0], t1 = b4[1], t2 = b4[2];
#pragma unroll 1
    for (int j = 0; j < 64; ++j) {
      float h3 = fmaxf(dot64(W3p + j * 64, h2) + c3[j], 0.f);
      t0 = fmaf(W4[j], h3, t0);
      t1 = fmaf(W4[64 + j], h3, t1);
      t2 = fmaf(W4[128 + j], h3, t2);
    }
    out[3 * r + 0] = t0;
    out[3 * r + 1] = t1;
    out[3 * r + 2] = t2;
    float s0, c0v, s1, c1v, s12, c12;
    sincosf(t0, &s0, &c0v);
    sincosf(t1, &s1, &c1v);
    sincosf(t1 + t2, &s12, &c12);
    float A = fmaf(0.115f, c12, 0.12f * c1v);
    size_t o2 = (size_t)3 * B + 3 * r;
    out[o2 + 0] = c0v * A;
    out[o2 + 1] = s0 * A;
    out[o2 + 2] = fmaf(0.115f, s12, 0.12f * s1);
  }
}

// ===========================================================================

extern "C" void kernel_launch(void* const* d_in, const int* in_sizes, int n_in,
                              void* d_out, int out_size, void* d_ws, size_t ws_size,
                              hipStream_t stream) {
  const float* x = (const float*)d_in[0];
  const float* W1 = (const float*)d_in[1];
  const float* b1 = (const float*)d_in[2];
  const float* g1 = (const float*)d_in[3];
  const float* be1 = (const float*)d_in[4];
  const float* W2 = (const float*)d_in[5];
  const float* b2 = (const float*)d_in[6];
  const float* g2 = (const float*)d_in[7];
  const float* be2 = (const float*)d_in[8];
  const float* W3 = (const float*)d_in[9];
  const float* b3 = (const float*)d_in[10];
  const float* g3 = (const float*)d_in[11];
  const float* be3 = (const float*)d_in[12];
  const float* W4 = (const float*)d_in[13];
  const float* b4 = (const float*)d_in[14];
  float* ws = (float*)d_ws;
  float* out = (float*)d_out;
  int B = in_sizes[0] / 3;

  hipMemsetAsync(d_ws, 0, 272 * sizeof(float), stream);

  const int blocks = 1024, thr = 256;
  const int zblocks = 2048;
  size_t need = 65536 + (size_t)B * 64 * 2;

  k_stats_x<<<blocks, thr, 0, stream>>>(x, ws, B);
  k_fin1<<<1, 64, 0, stream>>>(W1, b1, g1, be1, ws, B);

  if (ws_size >= need) {
    unsigned short* zb = (unsigned short*)ws + ZB_U16;
    k_z2<<<zblocks, thr, 0, stream>>>(x, W2, b2, ws, zb, B);
    k_fin_bn<<<1, 64, 0, stream>>>(ws + WS_SUM2, ws + WS_SSQ2, g2, be2,
                                   ws + FP_S2, ws + FP_C2, B);
    k_z3<<<zblocks, thr, 0, stream>>>(W3, b3, ws, zb, B);
    k_fin_bn<<<1, 64, 0, stream>>>(ws + WS_SUM3, ws + WS_SSQ3, g3, be3,
                                   ws + FP_S3, ws + FP_C3, B);
    k_final_fast<<<zblocks, thr, 0, stream>>>(zb, W4, b4, ws, out, B);
  } else {
    k_stats2_rc<<<blocks, thr, 0, stream>>>(x, W2, b2, ws, B);
    k_fin_dense_rc<<<1, 64, 0, stream>>>(W2, b2, g2, be2, ws + WS_SUM2, ws + WS_SSQ2,
                                         ws + RC_W2P, ws + RC_C2, B);
    k_stats3_rc<<<blocks, thr, 0, stream>>>(x, W3, b3, ws, B);
    k_fin_dense_rc<<<1, 64, 0, stream>>>(W3, b3, g3, be3, ws + WS_SUM3, ws + WS_SSQ3,
                                         ws + RC_W3P, ws + RC_C3, B);
    k_final_rc<<<blocks, thr, 0, stream>>>(x, W4, b4, ws, out, B);
  }
}

// Round 12
// 490.947 us; speedup vs baseline: 4.6707x; 2.4755x over previous
//
#include <hip/hip_runtime.h>
#include <math.h>

// ---------------------------------------------------------------------------
// InvKin (R19 = R11 revert, final).
// Session history: R9 fused BN stats into the z-producers (947->605us),
// R11 moved to single-row threads at natural register fit (529->489us).
// Subsequent falsified attempts (each with counter-verified post-mortem):
//  - R12-R14 MFMA: mfma_32x32x16_bf16 A/B fragment k-map symmetry
//    assumption wrong on this HW (absmax ~5 structural, twice, after
//    eliminating shuffles + aliasing UB). No cheap on-device probe here.
//  - R15 v_pk_fma_f32: packed fp32 is 4cyc/wave64 (2x work, same 32-wide
//    ALU) -> zero throughput gain; busy time rose.
//  - R16 forced 64-VGPR fit: scratch spill (FETCH 350MB), 4.7x slower.
//    Natural demand ~80 VGPR; forced caps below it always lose.
//  - R17/R18 vmcnt-domain weight loads: s_load weight fetch (one scalar
//    op/wave, SGPR broadcast) was the EFFICIENT part; per-lane vector
//    loads 2.5x slower. lgkm-coupling theory falsified.
// Remaining wall ~2.3x VALU-busy at 3 waves/EU is a structural latency
// plateau of the fp32-VALU design (memory floor ~90us << 489us; compute
// floor ~65-85us/heavy kernel). This is the session optimum: 489us, 33%
// faster than the 727us starting point.
//   P1 k_stats_x : x second moments (layer-1 BN stats analytic)
//   P2 k_fin1    : fold BN1 -> fp32 W1p[64][3] + c1[64]
//   P3 k_z2      : h1 -> raw z2 -> bf16 planes + fused BN2 stats
//   P4 k_fin_bn  : s2,c2
//   P5 k_z3      : h2 = relu(s2*z2+c2); z3 = W3 h2 + b3 + fused BN3 stats
//   P6 k_fin_bn  : s3,c3
//   P7 k_final   : h3 -> head -> closed-form FK -> out
// Fallback path (small ws): exact R1 kernel set (verified PASS).
// ---------------------------------------------------------------------------

static constexpr float kEps = 1e-5f;

#define HEAVY_BOUNDS __launch_bounds__(256) __attribute__((amdgpu_waves_per_eu(3, 4)))

// shared ws fp32 indices (both paths)
#define WS_STAT9 0
#define WS_SUM2  16
#define WS_SSQ2  80
#define WS_SUM3  144
#define WS_SSQ3  208
#define WS_W1P   288    // [64][3] fp32 (BN1-folded)
#define WS_C1    480    // [64]
// fast path only
#define FP_S2    8192
#define FP_C2    8256
#define FP_S3    8320
#define FP_C3    8384
// fallback (R1) only — may overlap FP_* since only one path ever runs
#define RC_W2P   544
#define RC_C2    4640
#define RC_W3P   4704
#define RC_C3    8800
// z buffer: byte offset 65536 (ushort index 32768)
#define ZB_U16   32768

// packed bf16x2 convert, round-to-nearest-even
__device__ __forceinline__ unsigned packbf2(float a, float b) {
  unsigned r;
  asm("v_cvt_pk_bf16_f32 %0, %1, %2" : "=v"(r) : "v"(a), "v"(b));
  return r;
}
__device__ __forceinline__ void unpack2(unsigned w, float& lo, float& hi) {
  lo = __builtin_bit_cast(float, w << 16);
  hi = __builtin_bit_cast(float, w & 0xffff0000u);
}

__device__ __forceinline__ float wred64(float v) {
  v += __shfl_xor(v, 32, 64);
  v += __shfl_xor(v, 16, 64);
  v += __shfl_xor(v, 8, 64);
  v += __shfl_xor(v, 4, 64);
  v += __shfl_xor(v, 2, 64);
  v += __shfl_xor(v, 1, 64);
  return v;
}

// butterfly reduce-scatter over 8 values: returns the full 64-lane sum of
// v[lane&7]. Levels 1/2/4 reduce-scatter the 8 units across the 8-lane
// group; levels 8/16/32 all-reduce the survivor across the 8 groups.
__device__ __forceinline__ float rs8(const float* v, int lane) {
  int b0 = lane & 1, b1 = (lane >> 1) & 1, b2 = (lane >> 2) & 1;
  float r[4];
#pragma unroll
  for (int i = 0; i < 4; ++i) {
    float keep = b0 ? v[2 * i + 1] : v[2 * i];
    float send = b0 ? v[2 * i] : v[2 * i + 1];
    r[i] = keep + __shfl_xor(send, 1, 64);
  }
  float t[2];
#pragma unroll
  for (int i = 0; i < 2; ++i) {
    float keep = b1 ? r[2 * i + 1] : r[2 * i];
    float send = b1 ? r[2 * i] : r[2 * i + 1];
    t[i] = keep + __shfl_xor(send, 2, 64);
  }
  float keep = b2 ? t[1] : t[0];
  float send = b2 ? t[0] : t[1];
  float u = keep + __shfl_xor(send, 4, 64);
  u += __shfl_xor(u, 8, 64);
  u += __shfl_xor(u, 16, 64);
  u += __shfl_xor(u, 32, 64);
  return u;
}

__device__ __forceinline__ float dot64(const float* __restrict__ wr,
                                       const float hin[64]) {
  float a0 = 0.f, a1 = 0.f, a2 = 0.f, a3 = 0.f;
#pragma unroll
  for (int k = 0; k < 64; k += 4) {
    a0 = fmaf(wr[k + 0], hin[k + 0], a0);
    a1 = fmaf(wr[k + 1], hin[k + 1], a1);
    a2 = fmaf(wr[k + 2], hin[k + 2], a2);
    a3 = fmaf(wr[k + 3], hin[k + 3], a3);
  }
  return (a0 + a1) + (a2 + a3);
}

// fused BN stats for one jb-block of 8 units, scalar-z form.
// lane l accumulates global unit (l>>3)*8 + (l&7) == l  (identity map).
__device__ __forceinline__ void stat_rs8s(const float* __restrict__ z, int jb,
                                          int lane, float w,
                                          float& sacc, float& qacc) {
  float s8[8], q8[8];
#pragma unroll
  for (int u = 0; u < 8; ++u) {
    s8[u] = w * z[u];
    q8[u] = s8[u] * z[u];
  }
  float sv = rs8(s8, lane);
  float qv = rs8(q8, lane);
  if ((lane >> 3) == jb) {
    sacc += sv;
    qacc += qv;
  }
}

__device__ __forceinline__ void block_combine_rc(float accS, float accQ,
                                                 float* __restrict__ sumg,
                                                 float* __restrict__ ssqg) {
  __shared__ float sS[256], sQ[256];
  sS[threadIdx.x] = accS;
  sQ[threadIdx.x] = accQ;
  __syncthreads();
  if (threadIdx.x < 64) {
    float S = sS[threadIdx.x] + sS[threadIdx.x + 64] + sS[threadIdx.x + 128] + sS[threadIdx.x + 192];
    float Q = sQ[threadIdx.x] + sQ[threadIdx.x + 64] + sQ[threadIdx.x + 128] + sQ[threadIdx.x + 192];
    atomicAdd(&sumg[threadIdx.x], S);
    atomicAdd(&ssqg[threadIdx.x], Q);
  }
}

// ---- P1: x second moments (shared) ---------------------------------------
__global__ void __launch_bounds__(256) k_stats_x(const float* __restrict__ x,
                                                 float* __restrict__ ws, int B) {
  int tid = blockIdx.x * 256 + threadIdx.x;
  int nt = gridDim.x * 256;
  float s0 = 0.f, s1 = 0.f, s2 = 0.f;
  float q00 = 0.f, q01 = 0.f, q02 = 0.f, q11 = 0.f, q12 = 0.f, q22 = 0.f;
  for (int r = tid; r < B; r += nt) {
    float x0 = x[3 * r], x1 = x[3 * r + 1], x2 = x[3 * r + 2];
    s0 += x0; s1 += x1; s2 += x2;
    q00 = fmaf(x0, x0, q00); q01 = fmaf(x0, x1, q01); q02 = fmaf(x0, x2, q02);
    q11 = fmaf(x1, x1, q11); q12 = fmaf(x1, x2, q12); q22 = fmaf(x2, x2, q22);
  }
  s0 = wred64(s0); s1 = wred64(s1); s2 = wred64(s2);
  q00 = wred64(q00); q01 = wred64(q01); q02 = wred64(q02);
  q11 = wred64(q11); q12 = wred64(q12); q22 = wred64(q22);
  __shared__ float part[9];
  if (threadIdx.x < 9) part[threadIdx.x] = 0.f;
  __syncthreads();
  if ((threadIdx.x & 63) == 0) {
    atomicAdd(&part[0], s0); atomicAdd(&part[1], s1); atomicAdd(&part[2], s2);
    atomicAdd(&part[3], q00); atomicAdd(&part[4], q01); atomicAdd(&part[5], q02);
    atomicAdd(&part[6], q11); atomicAdd(&part[7], q12); atomicAdd(&part[8], q22);
  }
  __syncthreads();
  if (threadIdx.x < 9) atomicAdd(&ws[WS_STAT9 + threadIdx.x], part[threadIdx.x]);
}

// ---- P2: fold BN1 (shared) ------------------------------------------------
__global__ void k_fin1(const float* __restrict__ W1, const float* __restrict__ b1,
                       const float* __restrict__ g1, const float* __restrict__ be1,
                       float* __restrict__ ws, int B) {
  int j = threadIdx.x;  // 64
  float inv = 1.0f / (float)B;
  float ex0 = ws[0] * inv, ex1 = ws[1] * inv, ex2 = ws[2] * inv;
  float c00 = ws[3] * inv - ex0 * ex0;
  float c01 = ws[4] * inv - ex0 * ex1;
  float c02 = ws[5] * inv - ex0 * ex2;
  float c11 = ws[6] * inv - ex1 * ex1;
  float c12 = ws[7] * inv - ex1 * ex2;
  float c22 = ws[8] * inv - ex2 * ex2;
  float w0 = W1[3 * j], w1 = W1[3 * j + 1], w2 = W1[3 * j + 2];
  float mean = w0 * ex0 + w1 * ex1 + w2 * ex2 + b1[j];
  float var = w0 * w0 * c00 + w1 * w1 * c11 + w2 * w2 * c22 +
              2.f * (w0 * w1 * c01 + w0 * w2 * c02 + w1 * w2 * c12);
  float s = g1[j] * rsqrtf(var + kEps);
  ws[WS_W1P + 3 * j + 0] = s * w0;
  ws[WS_W1P + 3 * j + 1] = s * w1;
  ws[WS_W1P + 3 * j + 2] = s * w2;
  ws[WS_C1 + j] = fmaf(s, b1[j] - mean, be1[j]);
}

// =========================== FAST PATH =====================================
// zbuf layout: 8 planes; plane jb is [B] x uint4, holding bf16 z-values for
// units jb*8 .. jb*8+7 of every row (low16 of word = even unit).
// Single row per thread; plane accesses are 64-consecutive-lane x 16B.

// ---- P3: z2 = W2 h1 + b2 -> bf16 planes + fused BN2 stats ----------------
__global__ void HEAVY_BOUNDS k_z2(const float* __restrict__ x,
                                  const float* __restrict__ W2,
                                  const float* __restrict__ b2,
                                  float* __restrict__ ws,
                                  unsigned short* __restrict__ zb, int B) {
  const float* W1p = ws + WS_W1P;
  const float* c1 = ws + WS_C1;
  uint4* __restrict__ zp = (uint4*)zb;
  int tid = blockIdx.x * 256 + threadIdx.x;
  int nt = gridDim.x * 256;
  int lane = threadIdx.x & 63;
  float sacc = 0.f, qacc = 0.f;
  int iters = (B + nt - 1) / nt;
  for (int it = 0; it < iters; ++it) {
    int r = tid + it * nt;
    bool valid = (r < B);
    int rc = valid ? r : (B - 1);
    float w = valid ? 1.f : 0.f;
    float x0 = x[3 * rc], x1 = x[3 * rc + 1], x2 = x[3 * rc + 2];
    float h[64];
#pragma unroll
    for (int k = 0; k < 64; ++k) {
      float z = fmaf(W1p[3 * k + 2], x2,
                 fmaf(W1p[3 * k + 1], x1, fmaf(W1p[3 * k], x0, c1[k])));
      h[k] = fmaxf(z, 0.f);
    }
#pragma unroll 1
    for (int jb = 0; jb < 8; ++jb) {
      float z[8];
#pragma unroll
      for (int u = 0; u < 8; ++u) {
        int j = jb * 8 + u;
        z[u] = dot64(W2 + j * 64, h) + b2[j];
      }
      stat_rs8s(z, jb, lane, w, sacc, qacc);
      if (valid) {
        uint4 o;
        o.x = packbf2(z[0], z[1]); o.y = packbf2(z[2], z[3]);
        o.z = packbf2(z[4], z[5]); o.w = packbf2(z[6], z[7]);
        zp[(size_t)jb * B + r] = o;
      }
    }
  }
  block_combine_rc(sacc, qacc, ws + WS_SUM2, ws + WS_SSQ2);
}

// ---- P4/P6: BN scale/shift only ------------------------------------------
__global__ void k_fin_bn(const float* __restrict__ sum, const float* __restrict__ ssq,
                         const float* __restrict__ g, const float* __restrict__ be,
                         float* __restrict__ sOut, float* __restrict__ cOut, int B) {
  int j = threadIdx.x;  // 64
  float inv = 1.0f / (float)B;
  float mean = sum[j] * inv;
  float var = ssq[j] * inv - mean * mean;
  float s = g[j] * rsqrtf(var + kEps);
  sOut[j] = s;
  cOut[j] = fmaf(-s, mean, be[j]);
}

// ---- P5: z3 = W3 relu(s2*z2+c2) + b3, in place + fused BN3 stats ---------
__global__ void HEAVY_BOUNDS k_z3(const float* __restrict__ W3,
                                  const float* __restrict__ b3,
                                  float* __restrict__ ws,
                                  unsigned short* __restrict__ zb, int B) {
  const float* s2 = ws + FP_S2;
  const float* c2 = ws + FP_C2;
  uint4* __restrict__ zp = (uint4*)zb;
  int tid = blockIdx.x * 256 + threadIdx.x;
  int nt = gridDim.x * 256;
  int lane = threadIdx.x & 63;
  float sacc = 0.f, qacc = 0.f;
  int iters = (B + nt - 1) / nt;
  for (int it = 0; it < iters; ++it) {
    int r = tid + it * nt;
    bool valid = (r < B);
    int rc = valid ? r : (B - 1);
    float w = valid ? 1.f : 0.f;
    float h[64];
#pragma unroll
    for (int o = 0; o < 8; ++o) {
      uint4 v = zp[(size_t)o * B + rc];
      float a, b;
      unpack2(v.x, a, b);
      h[8 * o + 0] = fmaxf(fmaf(s2[8 * o + 0], a, c2[8 * o + 0]), 0.f);
      h[8 * o + 1] = fmaxf(fmaf(s2[8 * o + 1], b, c2[8 * o + 1]), 0.f);
      unpack2(v.y, a, b);
      h[8 * o + 2] = fmaxf(fmaf(s2[8 * o + 2], a, c2[8 * o + 2]), 0.f);
      h[8 * o + 3] = fmaxf(fmaf(s2[8 * o + 3], b, c2[8 * o + 3]), 0.f);
      unpack2(v.z, a, b);
      h[8 * o + 4] = fmaxf(fmaf(s2[8 * o + 4], a, c2[8 * o + 4]), 0.f);
      h[8 * o + 5] = fmaxf(fmaf(s2[8 * o + 5], b, c2[8 * o + 5]), 0.f);
      unpack2(v.w, a, b);
      h[8 * o + 6] = fmaxf(fmaf(s2[8 * o + 6], a, c2[8 * o + 6]), 0.f);
      h[8 * o + 7] = fmaxf(fmaf(s2[8 * o + 7], b, c2[8 * o + 7]), 0.f);
    }
#pragma unroll 1
    for (int jb = 0; jb < 8; ++jb) {
      float z[8];
#pragma unroll
      for (int u = 0; u < 8; ++u) {
        int j = jb * 8 + u;
        z[u] = dot64(W3 + j * 64, h) + b3[j];
      }
      stat_rs8s(z, jb, lane, w, sacc, qacc);
      if (valid) {
        uint4 o;
        o.x = packbf2(z[0], z[1]); o.y = packbf2(z[2], z[3]);
        o.z = packbf2(z[4], z[5]); o.w = packbf2(z[6], z[7]);
        zp[(size_t)jb * B + r] = o;
      }
    }
  }
  block_combine_rc(sacc, qacc, ws + WS_SUM3, ws + WS_SSQ3);
}

// ---- P7: h3 -> head -> FK -> out -----------------------------------------
__global__ void HEAVY_BOUNDS k_final_fast(const unsigned short* __restrict__ zb,
                                          const float* __restrict__ W4,
                                          const float* __restrict__ b4,
                                          const float* __restrict__ ws,
                                          float* __restrict__ out, int B) {
  const float* s3 = ws + FP_S3;
  const float* c3 = ws + FP_C3;
  const uint4* __restrict__ zp = (const uint4*)zb;
  int tid = blockIdx.x * 256 + threadIdx.x;
  int nt = gridDim.x * 256;
  for (int r = tid; r < B; r += nt) {
    float h[64];
#pragma unroll
    for (int jb = 0; jb < 8; ++jb) {
      uint4 v = zp[(size_t)jb * B + r];
      unpack2(v.x, h[jb * 8 + 0], h[jb * 8 + 1]);
      unpack2(v.y, h[jb * 8 + 2], h[jb * 8 + 3]);
      unpack2(v.z, h[jb * 8 + 4], h[jb * 8 + 5]);
      unpack2(v.w, h[jb * 8 + 6], h[jb * 8 + 7]);
    }
#pragma unroll
    for (int k = 0; k < 64; ++k)
      h[k] = fmaxf(fmaf(s3[k], h[k], c3[k]), 0.f);
    float t0 = dot64(W4, h) + b4[0];
    float t1 = dot64(W4 + 64, h) + b4[1];
    float t2 = dot64(W4 + 128, h) + b4[2];
    out[3 * r + 0] = t0;
    out[3 * r + 1] = t1;
    out[3 * r + 2] = t2;
    float s0, c0v, s1, c1v, s12, c12;
    sincosf(t0, &s0, &c0v);
    sincosf(t1, &s1, &c1v);
    sincosf(t1 + t2, &s12, &c12);
    float A = fmaf(0.115f, c12, 0.12f * c1v);
    size_t o2 = (size_t)3 * B + 3 * r;
    out[o2 + 0] = c0v * A;
    out[o2 + 1] = s0 * A;
    out[o2 + 2] = fmaf(0.115f, s12, 0.12f * s1);
  }
}

// ========================= FALLBACK (R1, verified) =========================

__device__ __forceinline__ void layer1_eval(const float* __restrict__ W1p,
                                            const float* __restrict__ c1,
                                            float x0, float x1, float x2,
                                            float h[64]) {
#pragma unroll
  for (int j = 0; j < 64; ++j) {
    float z = fmaf(W1p[3 * j + 2], x2,
               fmaf(W1p[3 * j + 1], x1, fmaf(W1p[3 * j], x0, c1[j])));
    h[j] = fmaxf(z, 0.f);
  }
}

__device__ __forceinline__ void dense_relu_rc(const float* __restrict__ Wp,
                                              const float* __restrict__ c,
                                              const float hin[64], float hout[64]) {
#pragma unroll
  for (int j = 0; j < 64; ++j)
    hout[j] = fmaxf(dot64(Wp + j * 64, hin) + c[j], 0.f);
}

__device__ __forceinline__ void dense_stats_rc(const float* __restrict__ W,
                                               const float* __restrict__ b,
                                               const float hin[64], int lane,
                                               float valid, float& accS, float& accQ) {
#pragma unroll 1
  for (int j = 0; j < 64; ++j) {
    float z = (dot64(W + j * 64, hin) + b[j]) * valid;
    float rs = wred64(z);
    float rq = wred64(z * z);
    accS += (lane == j) ? rs : 0.f;
    accQ += (lane == j) ? rq : 0.f;
  }
}

__global__ void __launch_bounds__(256) k_stats2_rc(const float* __restrict__ x,
                                                   const float* __restrict__ W2,
                                                   const float* __restrict__ b2,
                                                   float* __restrict__ ws, int B) {
  const float* W1p = ws + WS_W1P;
  const float* c1 = ws + WS_C1;
  int tid = blockIdx.x * 256 + threadIdx.x;
  int nt = gridDim.x * 256;
  int lane = threadIdx.x & 63;
  float accS = 0.f, accQ = 0.f;
  int iters = (B + nt - 1) / nt;
  for (int it = 0; it < iters; ++it) {
    int r = tid + it * nt;
    float valid = (r < B) ? 1.f : 0.f;
    int rc = (r < B) ? r : (B - 1);
    float h1[64];
    layer1_eval(W1p, c1, x[3 * rc], x[3 * rc + 1], x[3 * rc + 2], h1);
    dense_stats_rc(W2, b2, h1, lane, valid, accS, accQ);
  }
  block_combine_rc(accS, accQ, ws + WS_SUM2, ws + WS_SSQ2);
}

__global__ void k_fin_dense_rc(const float* __restrict__ W, const float* __restrict__ b,
                               const float* __restrict__ g, const float* __restrict__ be,
                               const float* __restrict__ sum, const float* __restrict__ ssq,
                               float* __restrict__ Wp, float* __restrict__ cc, int B) {
  int j = threadIdx.x;
  float inv = 1.0f / (float)B;
  float mean = sum[j] * inv;
  float var = ssq[j] * inv - mean * mean;
  float s = g[j] * rsqrtf(var + kEps);
  for (int k = 0; k < 64; ++k) Wp[j * 64 + k] = s * W[j * 64 + k];
  cc[j] = fmaf(s, b[j] - mean, be[j]);
}

__global__ void __launch_bounds__(256) k_stats3_rc(const float* __restrict__ x,
                                                   const float* __restrict__ W3,
                                                   const float* __restrict__ b3,
                                                   float* __restrict__ ws, int B) {
  const float* W1p = ws + WS_W1P;
  const float* c1 = ws + WS_C1;
  const float* W2p = ws + RC_W2P;
  const float* c2 = ws + RC_C2;
  int tid = blockIdx.x * 256 + threadIdx.x;
  int nt = gridDim.x * 256;
  int lane = threadIdx.x & 63;
  float accS = 0.f, accQ = 0.f;
  int iters = (B + nt - 1) / nt;
  for (int it = 0; it < iters; ++it) {
    int r = tid + it * nt;
    float valid = (r < B) ? 1.f : 0.f;
    int rc = (r < B) ? r : (B - 1);
    float h1[64], h2[64];
    layer1_eval(W1p, c1, x[3 * rc], x[3 * rc + 1], x[3 * rc + 2], h1);
    dense_relu_rc(W2p, c2, h1, h2);
    dense_stats_rc(W3, b3, h2, lane, valid, accS, accQ);
  }
  block_combine_rc(accS, accQ, ws + WS_SUM3, ws + WS_SSQ3);
}

__global__ void __launch_bounds__(256) k_final_rc(const float* __restrict__ x,
                                                  const float* __restrict__ W4,
                                                  const float* __restrict__ b4,
                                                  const float* __restrict__ ws,
                                                  float* __restrict__ out, int B) {
  const float* W1p = ws + WS_W1P;
  const float* c1 = ws + WS_C1;
  const float* W2p = ws + RC_W2P;
  const float* c2 = ws + RC_C2;
  const float* W3p = ws + RC_W3P;
  const float* c3 = ws + RC_C3;
  int tid = blockIdx.x * 256 + threadIdx.x;
  int nt = gridDim.x * 256;
  for (int r = tid; r < B; r += nt) {
    float h1[64], h2[64];
    layer1_eval(W1p, c1, x[3 * r], x[3 * r + 1], x[3 * r + 2], h1);
    dense_relu_rc(W2p, c2, h1, h2);
    float t0 = b4[0], t1 = b4[1], t2 = b4[2];
#pragma unroll 1
    for (int j = 0; j < 64; ++j) {
      float h3 = fmaxf(dot64(W3p + j * 64, h2) + c3[j], 0.f);
      t0 = fmaf(W4[j], h3, t0);
      t1 = fmaf(W4[64 + j], h3, t1);
      t2 = fmaf(W4[128 + j], h3, t2);
    }
    out[3 * r + 0] = t0;
    out[3 * r + 1] = t1;
    out[3 * r + 2] = t2;
    float s0, c0v, s1, c1v, s12, c12;
    sincosf(t0, &s0, &c0v);
    sincosf(t1, &s1, &c1v);
    sincosf(t1 + t2, &s12, &c12);
    float A = fmaf(0.115f, c12, 0.12f * c1v);
    size_t o2 = (size_t)3 * B + 3 * r;
    out[o2 + 0] = c0v * A;
    out[o2 + 1] = s0 * A;
    out[o2 + 2] = fmaf(0.115f, s12, 0.12f * s1);
  }
}

// ===========================================================================

extern "C" void kernel_launch(void* const* d_in, const int* in_sizes, int n_in,
                              void* d_out, int out_size, void* d_ws, size_t ws_size,
                              hipStream_t stream) {
  const float* x = (const float*)d_in[0];
  const float* W1 = (const float*)d_in[1];
  const float* b1 = (const float*)d_in[2];
  const float* g1 = (const float*)d_in[3];
  const float* be1 = (const float*)d_in[4];
  const float* W2 = (const float*)d_in[5];
  const float* b2 = (const float*)d_in[6];
  const float* g2 = (const float*)d_in[7];
  const float* be2 = (const float*)d_in[8];
  const float* W3 = (const float*)d_in[9];
  const float* b3 = (const float*)d_in[10];
  const float* g3 = (const float*)d_in[11];
  const float* be3 = (const float*)d_in[12];
  const float* W4 = (const float*)d_in[13];
  const float* b4 = (const float*)d_in[14];
  float* ws = (float*)d_ws;
  float* out = (float*)d_out;
  int B = in_sizes[0] / 3;

  hipMemsetAsync(d_ws, 0, 272 * sizeof(float), stream);

  const int blocks = 1024, thr = 256;
  const int zblocks = 2048;
  size_t need = 65536 + (size_t)B * 64 * 2;

  k_stats_x<<<blocks, thr, 0, stream>>>(x, ws, B);
  k_fin1<<<1, 64, 0, stream>>>(W1, b1, g1, be1, ws, B);

  if (ws_size >= need) {
    unsigned short* zb = (unsigned short*)ws + ZB_U16;
    k_z2<<<zblocks, thr, 0, stream>>>(x, W2, b2, ws, zb, B);
    k_fin_bn<<<1, 64, 0, stream>>>(ws + WS_SUM2, ws + WS_SSQ2, g2, be2,
                                   ws + FP_S2, ws + FP_C2, B);
    k_z3<<<zblocks, thr, 0, stream>>>(W3, b3, ws, zb, B);
    k_fin_bn<<<1, 64, 0, stream>>>(ws + WS_SUM3, ws + WS_SSQ3, g3, be3,
                                   ws + FP_S3, ws + FP_C3, B);
    k_final_fast<<<zblocks, thr, 0, stream>>>(zb, W4, b4, ws, out, B);
  } else {
    k_stats2_rc<<<blocks, thr, 0, stream>>>(x, W2, b2, ws, B);
    k_fin_dense_rc<<<1, 64, 0, stream>>>(W2, b2, g2, be2, ws + WS_SUM2, ws + WS_SSQ2,
                                         ws + RC_W2P, ws + RC_C2, B);
    k_stats3_rc<<<blocks, thr, 0, stream>>>(x, W3, b3, ws, B);
    k_fin_dense_rc<<<1, 64, 0, stream>>>(W3, b3, g3, be3, ws + WS_SUM3, ws + WS_SSQ3,
                                         ws + RC_W3P, ws + RC_C3, B);
    k_final_rc<<<blocks, thr, 0, stream>>>(x, W4, b4, ws, out, B);
  }
}